// Round 21
// baseline (65.598 us; speedup 1.0000x reference)
//
#include <hip/hip_runtime.h>
#include <hip/hip_bf16.h>

// RDF with minimum-image PBC + Gaussian smearing, N=2048 atoms, 100 bins.
//
// Round-21: MEASUREMENT ROUND on the SOUND r20 base (r20 passed, 22.5us,
// absmax at the 0.0078 quantization floor; its handoff is provably
// race-free: memset-reset ticket -> winner is the TRUE last arriver).
// Body executed NREP=8 times (each rep re-zeros fine/cd and recomputes
// identical conv values; publish/handoff once -> output bit-identical to
// r20). Purpose: dur_us = 22.5 + 7*B isolates the true per-rep body cost
// B (invariant ~13us across 13 rounds of structural changes; issue-count
// model says ~4-5us @2.4GHz). B~13 linear => real stalls; B~5 =>
// clock-ramp (low DPM state for us-scale dispatches). And the kernel
// finally exceeds the 40us harness poison fills -> first-ever PMC row
// (VALUBusy / OccupancyPercent / SQ_LDS_BANK_CONFLICT) for this body.
//
// Body (= r13/r20): 256 blocks x 1024 threads; block owns 8 rows of the
// cyclic upper-triangle enumeration (j=(i+1+t) mod N; one predicate
// dedups the d==N/2 diagonal; x2 pair weight cancels in count
// normalization). i wave-uniform -> scalar i-loads; j-loads coalesced,
// L1-resident (xyz=24KB). ONE u32 LDS atomic per pair into a FINE
// distance histogram (17 sub-bins/bin, 4 private copies; integer counts
// -> exact, order-independent). Epilogue merges copies + convolves with
// a 103-tap Gaussian (stride 17 coprime with 32 banks -> conflict-free).
// Pairs with dist < 8 bin-units (~250 device-wide) take an exact f32
// direct-smear path into bins 0..11.
// Handoff (= r20, SOUND): returning atomicExch publish (swaps performed
// at the IF before the vmcnt-draining barrier) -> relaxed flat ticket
// (memset-reset each call; winner so==255 is the true last arriver; all
// 255 prior RMWs are real-time-after their blocks' IF-performed swaps)
// -> winner does one ACQUIRE + system-scope relaxed readback (reads at
// the IF), fixed-order reduce -> deterministic.
// d_out = [count(100) | bins(101) | rdf(100)]. Graph = 4B memset node +
// one kernel node.

#define N_ATOMS 2048
#define HALF    1024
#define NBINS   100
#define S_FINE  17          // fine sub-bins per coarse bin (coprime with 32)
#define FBINS   1744        // > 102.5 * 17 = 1742.5
#define NCOPY   4           // private fine-histogram copies
#define TAPS    103         // 2*3*17 + 1  (window +-3 bin widths)
#define NDIR    12          // exact direct-path coarse bins 0..11
#define TLOW    8.0f        // bin-units: below this, take the exact path
#define NBLOCKS 256
#define NTHREADS 1024
#define ROWS_PB 8           // N_ATOMS / NBLOCKS
#define PADB    112         // padded row stride for publish slots
#define NREP    8           // measurement multiplier (deterministic repeats)

__global__ __launch_bounds__(1024) void rdf_fused(
    const float* __restrict__ xyz,
    const float* __restrict__ cell,
    const float* __restrict__ offsets,
    const float* __restrict__ bins,
    float* __restrict__ out,
    float* __restrict__ partials,   // [NBLOCKS][PADB], exch-overwritten
    unsigned* __restrict__ ticket)  // RESET to 0 each call by memset node
{
    __shared__ unsigned fine[NCOPY][FBINS];  // private fine histograms (u32)
    __shared__ float wtab[TAPS];             // Gaussian taps
    __shared__ float conv[NBINS][8];         // conv partials / tail reduce
    __shared__ float cd[16];                 // exact direct-path coarse bins
    __shared__ float ssum[2];
    __shared__ unsigned stick;

    const int tid = threadIdx.x;
    const int bid = blockIdx.x;

    if (tid < TAPS) {
        const float u = ((float)tid - 50.5f) * (1.0f / (float)S_FINE);
        wtab[tid] = __expf(-0.5f * u * u);
    }

    const float cx = cell[0], cy = cell[1], cz = cell[2];
    const float hcx = 0.5f * cx, hcy = 0.5f * cy, hcz = 0.5f * cz;

    const float width = offsets[1] - offsets[0];   // 7.5/99
    const float invw  = 1.0f / width;
    const float cutd   = 102.5f * width;           // 7.765 < CUTOFF_B = 8.0
    const float cut2   = cutd * cutd;

    unsigned* const myfine = fine[tid >> 8];       // 4 waves per copy

    for (int rep = 0; rep < NREP; ++rep) {
        // re-zero per rep (deterministic identical repeats)
        for (int a = tid; a < NCOPY * FBINS; a += NTHREADS)
            (&fine[0][0])[a] = 0u;
        if (tid < 16) cd[tid] = 0.0f;
        __syncthreads();

        // ---- main loop: 8 rows per block, one 1024-wide j-sweep each ----
        const int row0 = bid << 3;
        #pragma unroll
        for (int r = 0; r < ROWS_PB; ++r) {
            const int i = row0 + r;                    // wave-uniform
            const float xi = xyz[3 * i + 0];           // scalar loads
            const float yi = xyz[3 * i + 1];
            const float zi = xyz[3 * i + 2];
            if (tid == HALF - 1 && i >= HALF) continue; // dedup N/2 diagonal
            const int j = (i + 1 + tid) & (N_ATOMS - 1);

            float dx = xyz[3 * j + 0] - xi;            // coalesced, L1-res
            float dy = xyz[3 * j + 1] - yi;
            float dz = xyz[3 * j + 2] - zi;
            // minimum-image wrap (matches reference shift semantics)
            dx += (dx >= hcx) ? -cx : ((dx < -hcx) ? cx : 0.0f);
            dy += (dy >= hcy) ? -cy : ((dy < -hcy) ? cy : 0.0f);
            dz += (dz >= hcz) ? -cz : ((dz < -hcz) ? cz : 0.0f);

            const float dsq = dx * dx + dy * dy + dz * dz;
            if (dsq < cut2 && dsq != 0.0f) {
                const float tu = sqrtf(dsq) * invw;    // dist in bin units
                if (tu >= TLOW) {
                    atomicAdd(&myfine[(int)(tu * (float)S_FINE)], 1u);
                } else {
                    int khi = (int)tu + 4; if (khi > NDIR - 1) khi = NDIR - 1;
                    for (int k = 0; k <= khi; ++k) {
                        const float e = tu - (float)k;
                        atomicAdd(&cd[k], __expf(-0.5f * e * e));
                    }
                }
            }
        }

        __syncthreads();

        // merge the 4 copies into copy 0 (stride-1, conflict-free)
        for (int a = tid; a < FBINS; a += NTHREADS)
            fine[0][a] += fine[1][a] + fine[2][a] + fine[3][a];
        __syncthreads();

        // coarse[k] = sum_d wtab[d+51] * fine[17k+d]; stride-17 reads are
        // bank-conflict free (gcd(17,32)=1)
        if (tid < 400) {
            const int k = tid >> 2;
            const int c = tid & 3;
            const int m0 = c * 26;
            const int mcnt = (c == 3) ? 25 : 26;
            float s = 0.0f;
            for (int mm = 0; mm < mcnt; ++mm) {
                const int m = m0 + mm;
                const int f = S_FINE * k + m - 51;     // max 1734
                if (f >= 0) s += wtab[m] * (float)fine[0][f];  // < 2^24
            }
            conv[k][c] = s;
        }
        __syncthreads();
    }

    // ---- publish (values identical every rep): RETURNING atomicExch.
    // Returning (sc0) form completes vmcnt only when the old value comes
    // back from the IF -> after the barrier all swaps are PERFORMED there.
    if (tid < NBINS) {
        float raw = conv[tid][0] + conv[tid][1] + conv[tid][2] + conv[tid][3];
        if (tid < NDIR) raw += cd[tid];
        float old = atomicExch(&partials[bid * PADB + tid], raw);
        asm volatile("" :: "v"(old));   // keep return value live (sc0 form)
    }

    __syncthreads();
    if (tid == 0) {
        const unsigned so = __hip_atomic_fetch_add(
            ticket, 1u, __ATOMIC_RELAXED, __HIP_MEMORY_SCOPE_AGENT);
        unsigned last = (so == NBLOCKS - 1) ? 1u : 0u;  // TRUE last arriver
        if (last) {
            // belt-and-braces single acquire (cache invalidate)
            __hip_atomic_fetch_add(ticket, 0u,
                                   __ATOMIC_ACQUIRE, __HIP_MEMORY_SCOPE_AGENT);
        }
        stick = last;
    }
    __syncthreads();
    if (!stick) return;

    // ---- winner (provably last): SYSTEM-scope relaxed readback at the
    // IF. thread t: bin b=t&127, chunk c=t>>7; 32 blocks each, fixed order.
    {
        const int b = tid & 127;
        const int c = tid >> 7;
        if (b < NBINS) {
            float s = 0.0f;
            #pragma unroll 8
            for (int q = 0; q < NBLOCKS / 8; ++q) {
                const int blk = c * (NBLOCKS / 8) + q;
                s += __hip_atomic_load(&partials[blk * PADB + b],
                                       __ATOMIC_RELAXED,
                                       __HIP_MEMORY_SCOPE_SYSTEM);
            }
            conv[b][c] = s;
        }
    }
    __syncthreads();

    float raw = 0.0f;
    if (tid < NBINS) {
        #pragma unroll
        for (int c = 0; c < 8; ++c) raw += conv[tid][c];
    }
    if (tid < 128) {
        float v = raw;
        #pragma unroll
        for (int o = 32; o > 0; o >>= 1) v += __shfl_down(v, o);
        if ((tid & 63) == 0) ssum[tid >> 6] = v;
    }
    __syncthreads();
    const float S = ssum[0] + ssum[1];

    if (tid < NBINS) {
        const float cnt = raw / S;
        out[tid] = cnt;                                // count
        const float b0 = bins[tid], b1 = bins[tid + 1];
        const float R  = bins[NBINS];                  // R_END = 7.5
        // rdf = cnt / (vol_bin / V) = cnt * R^3 / (b1^3 - b0^3)  (4pi/3 cancels)
        out[201 + tid] = cnt * (R * R * R) / (b1 * b1 * b1 - b0 * b0 * b0);
    }
    if (tid < NBINS + 1) {
        out[100 + tid] = bins[tid];                    // bins passthrough
    }
}

extern "C" void kernel_launch(void* const* d_in, const int* in_sizes, int n_in,
                              void* d_out, int out_size, void* d_ws, size_t ws_size,
                              hipStream_t stream) {
    const float* xyz     = (const float*)d_in[0];
    const float* cell    = (const float*)d_in[1];
    const float* bins    = (const float*)d_in[2];
    const float* offsets = (const float*)d_in[3];
    float* out = (float*)d_out;

    float*    partials = (float*)d_ws;   // NBLOCKS*PADB floats, exch-overwritten
    unsigned* ticket   = (unsigned*)((char*)d_ws +
                                     (size_t)NBLOCKS * PADB * sizeof(float));

    // reset the ticket each call: winner is then provably the LAST arriver
    hipMemsetAsync(ticket, 0, sizeof(unsigned), stream);
    rdf_fused<<<NBLOCKS, NTHREADS, 0, stream>>>(xyz, cell, offsets, bins, out,
                                                partials, ticket);
}

// Round 22
// 23.106 us; speedup vs baseline: 2.8390x; 2.8390x over previous
//
#include <hip/hip_runtime.h>
#include <hip/hip_bf16.h>

// RDF with minimum-image PBC + Gaussian smearing, N=2048 atoms, 100 bins.
//
// Round-22: HIERARCHICAL handoff on the sound r20 protocol.
// r21's NREP measurement overturned the body theory: marginal rep cost is
// ~6.2us (VALUBusy 35%, bank conflicts ~0.25us/rep) — the r20 kernel's
// missing ~15us is the HANDOFF: a flat 256-deep same-address ticket chain
// (~40ns/RMW serialized = ~10us, fully on the critical path since the
// winner is the TRUE last arriver) + one block's 3200-load readback
// (~3us). r11's two-level null was confounded by the poisoned-ticket bug.
// Now: 16 groups x 16 blocks (group = bid>>4).
//   L1: block exch-publishes its 100-bin row (returning exch = performed
//       at the IF before the vmcnt-drained barrier), then sub-ticket
//       fetch_add (relaxed; 16 chains drain IN PARALLEL, ~0.6us). The
//       group's true-last block (so==15; tickets memset-reset each call)
//       reads its group's 16 rows (system-scope relaxed at the IF, ~1us,
//       16 sub-winners in parallel), reduces in fixed order, and
//       exch-publishes ONE level-2 row.
//   L2: master ticket (16 arrivals); true-last sub-winner does one
//       ACQUIRE, reads the 16 level-2 rows, reduces in fixed order,
//       normalizes, writes d_out = [count(100) | bins(101) | rdf(100)].
// Which block performs each reduction varies run-to-run, but the VALUES
// are fixed-order sums -> deterministic output. Soundness per level is
// r20's argument: publishes are PERFORMED at the IF before the publisher's
// ticket RMW issues; the true-last RMW is real-time-after all others.
//
// Body (= r13/r20, ~6us): 256 blocks x 1024 threads; block owns 8 rows of
// the cyclic upper-triangle enumeration (j=(i+1+t) mod N; one predicate
// dedups the d==N/2 diagonal; x2 pair weight cancels in count
// normalization). i wave-uniform -> scalar i-loads; j-loads coalesced,
// L1-resident (xyz=24KB). ONE u32 LDS atomic per pair into a FINE distance
// histogram (17 sub-bins/bin, 4 private copies; integer counts -> exact,
// order-independent). Epilogue merges copies + convolves with a 103-tap
// Gaussian (stride 17 coprime with 32 banks -> conflict-free). Pairs with
// dist < 8 bin-units (~250 device-wide) take an exact f32 direct-smear
// path into bins 0..11 (tiny shell volumes amplify quantization error).
// Graph = one 4.1KB memset node (tickets) + one kernel node.

#define N_ATOMS 2048
#define HALF    1024
#define NBINS   100
#define S_FINE  17          // fine sub-bins per coarse bin (coprime with 32)
#define FBINS   1744        // > 102.5 * 17 = 1742.5
#define NCOPY   4           // private fine-histogram copies
#define TAPS    103         // 2*3*17 + 1  (window +-3 bin widths)
#define NDIR    12          // exact direct-path coarse bins 0..11
#define TLOW    8.0f        // bin-units: below this, take the exact path
#define NBLOCKS 256
#define NTHREADS 1024
#define ROWS_PB 8           // N_ATOMS / NBLOCKS
#define PADB    112         // padded row stride for publish slots
#define NSUB    16          // groups; GSZ = NBLOCKS/NSUB = 16 blocks each
#define GSZ     16
#define TSTRIDE 64          // words between ticket slots (256B apart)
// d_ws layout:
//   partials: NBLOCKS*PADB floats          (offset 0)
//   tickets : NSUB*TSTRIDE+1 unsigneds     (offset TICK_OFF)
//   l2      : NSUB*PADB floats             (offset L2_OFF)
#define TICK_OFF  (NBLOCKS * PADB * 4)
#define TICK_BYTES ((NSUB * TSTRIDE + 1) * 4)
#define L2_OFF    (TICK_OFF + 8192)

__global__ __launch_bounds__(1024) void rdf_fused(
    const float* __restrict__ xyz,
    const float* __restrict__ cell,
    const float* __restrict__ offsets,
    const float* __restrict__ bins,
    float* __restrict__ out,
    float* __restrict__ partials,   // [NBLOCKS][PADB], exch-overwritten
    unsigned* __restrict__ tickets, // NSUB subs + master; memset-reset
    float* __restrict__ l2)         // [NSUB][PADB], exch-overwritten
{
    __shared__ unsigned fine[NCOPY][FBINS];  // private fine histograms (u32)
    __shared__ float wtab[TAPS];             // Gaussian taps
    __shared__ float conv[NBINS][8];         // conv partials / reduces
    __shared__ float cd[16];                 // exact direct-path coarse bins
    __shared__ float ssum[2];
    __shared__ unsigned stick;

    const int tid = threadIdx.x;
    const int bid = blockIdx.x;

    for (int a = tid; a < NCOPY * FBINS; a += NTHREADS)
        (&fine[0][0])[a] = 0u;
    if (tid < 16)   cd[tid] = 0.0f;
    if (tid < TAPS) {
        const float u = ((float)tid - 50.5f) * (1.0f / (float)S_FINE);
        wtab[tid] = __expf(-0.5f * u * u);
    }
    __syncthreads();

    const float cx = cell[0], cy = cell[1], cz = cell[2];
    const float hcx = 0.5f * cx, hcy = 0.5f * cy, hcz = 0.5f * cz;

    const float width = offsets[1] - offsets[0];   // 7.5/99
    const float invw  = 1.0f / width;
    const float cutd   = 102.5f * width;           // 7.765 < CUTOFF_B = 8.0
    const float cut2   = cutd * cutd;

    unsigned* const myfine = fine[tid >> 8];       // 4 waves per copy

    // ---- main loop: 8 rows per block, one 1024-wide j-sweep per row ----
    const int row0 = bid << 3;
    #pragma unroll
    for (int r = 0; r < ROWS_PB; ++r) {
        const int i = row0 + r;                    // wave-uniform
        const float xi = xyz[3 * i + 0];           // scalar loads
        const float yi = xyz[3 * i + 1];
        const float zi = xyz[3 * i + 2];
        if (tid == HALF - 1 && i >= HALF) continue; // dedup N/2 diagonal
        const int j = (i + 1 + tid) & (N_ATOMS - 1);

        float dx = xyz[3 * j + 0] - xi;            // coalesced, L1-resident
        float dy = xyz[3 * j + 1] - yi;
        float dz = xyz[3 * j + 2] - zi;
        // minimum-image wrap (matches reference shift semantics)
        dx += (dx >= hcx) ? -cx : ((dx < -hcx) ? cx : 0.0f);
        dy += (dy >= hcy) ? -cy : ((dy < -hcy) ? cy : 0.0f);
        dz += (dz >= hcz) ? -cz : ((dz < -hcz) ? cz : 0.0f);

        const float dsq = dx * dx + dy * dy + dz * dz;
        if (dsq < cut2 && dsq != 0.0f) {
            const float tu = sqrtf(dsq) * invw;    // dist in bin units
            if (tu >= TLOW) {
                // ONE native u32 LDS atomic/pair; lanes scatter over 1744
                atomicAdd(&myfine[(int)(tu * (float)S_FINE)], 1u);
            } else {
                // exact f32 path for low bins (~250 pairs device-wide)
                int khi = (int)tu + 4; if (khi > NDIR - 1) khi = NDIR - 1;
                for (int k = 0; k <= khi; ++k) {
                    const float e = tu - (float)k;
                    atomicAdd(&cd[k], __expf(-0.5f * e * e));
                }
            }
        }
    }

    __syncthreads();

    // merge the 4 copies into copy 0 (stride-1, conflict-free, int adds)
    for (int a = tid; a < FBINS; a += NTHREADS)
        fine[0][a] += fine[1][a] + fine[2][a] + fine[3][a];
    __syncthreads();

    // coarse[k] = sum_d wtab[d+51] * fine[17k+d]; stride-17 reads are
    // bank-conflict free (gcd(17,32)=1)
    if (tid < 400) {
        const int k = tid >> 2;
        const int c = tid & 3;
        const int m0 = c * 26;
        const int mcnt = (c == 3) ? 25 : 26;
        float s = 0.0f;
        for (int mm = 0; mm < mcnt; ++mm) {
            const int m = m0 + mm;
            const int f = S_FINE * k + m - 51;     // max 17*99+51 = 1734
            if (f >= 0) s += wtab[m] * (float)fine[0][f];  // exact: < 2^24
        }
        conv[k][c] = s;
    }
    __syncthreads();

    // ---- L1 publish: RETURNING atomicExch (performed at the IF before
    // the vmcnt-draining barrier releases thread 0) ----
    if (tid < NBINS) {
        float raw = conv[tid][0] + conv[tid][1] + conv[tid][2] + conv[tid][3];
        if (tid < NDIR) raw += cd[tid];
        float old = atomicExch(&partials[bid * PADB + tid], raw);
        asm volatile("" :: "v"(old));   // keep return value live (sc0 form)
    }

    __syncthreads();
    const int g = bid >> 4;                        // group 0..15
    if (tid == 0) {
        const unsigned so = __hip_atomic_fetch_add(
            &tickets[g * TSTRIDE], 1u,
            __ATOMIC_RELAXED, __HIP_MEMORY_SCOPE_AGENT);
        unsigned subwin = (so == GSZ - 1) ? 1u : 0u;   // TRUE last in group
        if (subwin) {
            __hip_atomic_fetch_add(&tickets[g * TSTRIDE], 0u,
                                   __ATOMIC_ACQUIRE, __HIP_MEMORY_SCOPE_AGENT);
        }
        stick = subwin;
    }
    __syncthreads();
    if (!stick) return;

    // ---- sub-winner: reduce own group's 16 rows (system-scope at IF).
    // thread t: bin b=t&127, chunk c=t>>7 (0..7) -> rows g*16+2c, +2c+1.
    {
        const int b = tid & 127;
        const int c = tid >> 7;
        if (b < NBINS) {
            float s = 0.0f;
            #pragma unroll
            for (int qq = 0; qq < 2; ++qq) {
                const int blk = (g << 4) + (c << 1) + qq;   // ascending
                s += __hip_atomic_load(&partials[blk * PADB + b],
                                       __ATOMIC_RELAXED,
                                       __HIP_MEMORY_SCOPE_SYSTEM);
            }
            conv[b][c] = s;
        }
    }
    __syncthreads();

    // L2 publish: one row per group, returning exch
    if (tid < NBINS) {
        float s = 0.0f;
        #pragma unroll
        for (int c = 0; c < 8; ++c) s += conv[tid][c];     // ascending blocks
        float old = atomicExch(&l2[g * PADB + tid], s);
        asm volatile("" :: "v"(old));
    }

    __syncthreads();
    if (tid == 0) {
        const unsigned mo = __hip_atomic_fetch_add(
            &tickets[NSUB * TSTRIDE], 1u,
            __ATOMIC_RELAXED, __HIP_MEMORY_SCOPE_AGENT);
        unsigned last = (mo == NSUB - 1) ? 1u : 0u;        // TRUE last group
        if (last) {
            __hip_atomic_fetch_add(&tickets[NSUB * TSTRIDE], 0u,
                                   __ATOMIC_ACQUIRE, __HIP_MEMORY_SCOPE_AGENT);
        }
        stick = last;
    }
    __syncthreads();
    if (!stick) return;

    // ---- master winner: reduce the 16 level-2 rows (system-scope at IF).
    // thread t: bin b=t&127, chunk c=t>>7 -> groups 2c, 2c+1 (ascending).
    {
        const int b = tid & 127;
        const int c = tid >> 7;
        if (b < NBINS) {
            float s = 0.0f;
            #pragma unroll
            for (int qq = 0; qq < 2; ++qq) {
                const int g2 = (c << 1) + qq;
                s += __hip_atomic_load(&l2[g2 * PADB + b],
                                       __ATOMIC_RELAXED,
                                       __HIP_MEMORY_SCOPE_SYSTEM);
            }
            conv[b][c] = s;
        }
    }
    __syncthreads();

    float raw = 0.0f;
    if (tid < NBINS) {
        #pragma unroll
        for (int c = 0; c < 8; ++c) raw += conv[tid][c];   // ascending groups
    }
    if (tid < 128) {
        float v = raw;
        #pragma unroll
        for (int o = 32; o > 0; o >>= 1) v += __shfl_down(v, o);
        if ((tid & 63) == 0) ssum[tid >> 6] = v;
    }
    __syncthreads();
    const float S = ssum[0] + ssum[1];

    if (tid < NBINS) {
        const float cnt = raw / S;
        out[tid] = cnt;                                // count
        const float b0 = bins[tid], b1 = bins[tid + 1];
        const float R  = bins[NBINS];                  // R_END = 7.5
        // rdf = cnt / (vol_bin / V) = cnt * R^3 / (b1^3 - b0^3)  (4pi/3 cancels)
        out[201 + tid] = cnt * (R * R * R) / (b1 * b1 * b1 - b0 * b0 * b0);
    }
    if (tid < NBINS + 1) {
        out[100 + tid] = bins[tid];                    // bins passthrough
    }
}

extern "C" void kernel_launch(void* const* d_in, const int* in_sizes, int n_in,
                              void* d_out, int out_size, void* d_ws, size_t ws_size,
                              hipStream_t stream) {
    const float* xyz     = (const float*)d_in[0];
    const float* cell    = (const float*)d_in[1];
    const float* bins    = (const float*)d_in[2];
    const float* offsets = (const float*)d_in[3];
    float* out = (float*)d_out;

    float*    partials = (float*)d_ws;
    unsigned* tickets  = (unsigned*)((char*)d_ws + TICK_OFF);
    float*    l2       = (float*)((char*)d_ws + L2_OFF);

    // reset all tickets each call: every "last arriver" is provably last
    hipMemsetAsync(tickets, 0, TICK_BYTES, stream);
    rdf_fused<<<NBLOCKS, NTHREADS, 0, stream>>>(xyz, cell, offsets, bins, out,
                                                partials, tickets, l2);
}

// Round 23
// 17.684 us; speedup vs baseline: 3.7095x; 1.3066x over previous
//
#include <hip/hip_runtime.h>
#include <hip/hip_bf16.h>

// RDF with minimum-image PBC + Gaussian smearing, N=2048 atoms, 100 bins.
//
// Round-23: r20 (sound, 22.5us, absmax at the 0.0078 quantization floor)
// with the hipMemsetAsync ticket-reset node ELIMINATED. r22 proved the
// handoff STRUCTURE is not the residual (hierarchical == flat); r21's
// NREP measurement pinned the body at ~6.2us; the remaining suspect is
// the memset graph node itself (a real fillBufferAligned dispatch per
// replay — the profile shows those tiny fills as full dispatches).
// Replacement: block 0, thread 0 resets the ticket at the VERY TOP of
// the kernel with a RETURNING atomicExch(ticket, 0) (performed at the
// IF within ~1us of dispatch). Every other block's ticket RMW issues
// only after its ~6us body -> >=4us margin before any increment can
// race the reset. Steady-state soundness: ticket==0 at each replay
// start (graph replays are stream-serialized), so the winner so==255
// is provably the TRUE last arriver — r20's argument holds unchanged.
// Works for the correctness call too (garbage ticket is wiped by the
// exch before any arrival). Graph = ONE kernel node.
//
// Body (= r13/r20, ~6us): 256 blocks x 1024 threads; block owns 8 rows
// of the cyclic upper-triangle enumeration (j=(i+1+t) mod N; one
// predicate dedups the d==N/2 diagonal; x2 pair weight cancels in count
// normalization). i wave-uniform -> scalar i-loads; j-loads coalesced,
// L1-resident (xyz=24KB). ONE u32 LDS atomic per pair into a FINE
// distance histogram (17 sub-bins/bin, 4 private copies; integer counts
// -> exact, order-independent). Epilogue merges copies + convolves with
// a 103-tap Gaussian (stride 17 coprime with 32 banks -> conflict-free).
// Pairs with dist < 8 bin-units (~250 device-wide) take an exact f32
// direct-smear path into bins 0..11 (tiny shell volumes amplify
// quantization error there).
// Handoff (= r20): returning atomicExch publish (swaps performed at the
// IF before the vmcnt-drained barrier) -> relaxed flat ticket -> the
// true-last winner does one ACQUIRE + system-scope relaxed readback
// (reads at the IF), fixed-order reduce -> deterministic.
// d_out = [count(100) | bins(101) | rdf(100)].

#define N_ATOMS 2048
#define HALF    1024
#define NBINS   100
#define S_FINE  17          // fine sub-bins per coarse bin (coprime with 32)
#define FBINS   1744        // > 102.5 * 17 = 1742.5
#define NCOPY   4           // private fine-histogram copies
#define TAPS    103         // 2*3*17 + 1  (window +-3 bin widths)
#define NDIR    12          // exact direct-path coarse bins 0..11
#define TLOW    8.0f        // bin-units: below this, take the exact path
#define NBLOCKS 256
#define NTHREADS 1024
#define ROWS_PB 8           // N_ATOMS / NBLOCKS
#define PADB    112         // padded row stride for publish slots

__global__ __launch_bounds__(1024) void rdf_fused(
    const float* __restrict__ xyz,
    const float* __restrict__ cell,
    const float* __restrict__ offsets,
    const float* __restrict__ bins,
    float* __restrict__ out,
    float* __restrict__ partials,   // [NBLOCKS][PADB], exch-overwritten
    unsigned* __restrict__ ticket)  // reset by block 0's exch at kernel start
{
    __shared__ unsigned fine[NCOPY][FBINS];  // private fine histograms (u32)
    __shared__ float wtab[TAPS];             // Gaussian taps
    __shared__ float conv[NBINS][8];         // conv partials / tail reduce
    __shared__ float cd[16];                 // exact direct-path coarse bins
    __shared__ float ssum[2];
    __shared__ unsigned stick;

    const int tid = threadIdx.x;
    const int bid = blockIdx.x;

    // ---- in-kernel ticket reset: block 0 is dispatched first; its
    // returning exch is performed at the IF ~1us in, >=4us before any
    // other block's post-body ticket RMW can arrive ----
    if (bid == 0 && tid == 0) {
        unsigned oldt = atomicExch(ticket, 0u);
        asm volatile("" :: "v"(oldt));      // keep returning (sc0) form
    }

    for (int a = tid; a < NCOPY * FBINS; a += NTHREADS)
        (&fine[0][0])[a] = 0u;
    if (tid < 16)   cd[tid] = 0.0f;
    if (tid < TAPS) {
        const float u = ((float)tid - 50.5f) * (1.0f / (float)S_FINE);
        wtab[tid] = __expf(-0.5f * u * u);
    }
    __syncthreads();

    const float cx = cell[0], cy = cell[1], cz = cell[2];
    const float hcx = 0.5f * cx, hcy = 0.5f * cy, hcz = 0.5f * cz;

    const float width = offsets[1] - offsets[0];   // 7.5/99
    const float invw  = 1.0f / width;
    // beyond 102.5 bin-units no bin k<=99 lies within the +-3w window
    const float cutd   = 102.5f * width;           // 7.765 < CUTOFF_B = 8.0
    const float cut2   = cutd * cutd;

    unsigned* const myfine = fine[tid >> 8];       // 4 waves per copy

    // ---- main loop: 8 rows per block, one 1024-wide j-sweep per row ----
    const int row0 = bid << 3;
    #pragma unroll
    for (int r = 0; r < ROWS_PB; ++r) {
        const int i = row0 + r;                    // wave-uniform
        const float xi = xyz[3 * i + 0];           // scalar loads
        const float yi = xyz[3 * i + 1];
        const float zi = xyz[3 * i + 2];
        if (tid == HALF - 1 && i >= HALF) continue; // dedup N/2 diagonal
        const int j = (i + 1 + tid) & (N_ATOMS - 1);

        float dx = xyz[3 * j + 0] - xi;            // coalesced, L1-resident
        float dy = xyz[3 * j + 1] - yi;
        float dz = xyz[3 * j + 2] - zi;
        // minimum-image wrap (matches reference shift semantics)
        dx += (dx >= hcx) ? -cx : ((dx < -hcx) ? cx : 0.0f);
        dy += (dy >= hcy) ? -cy : ((dy < -hcy) ? cy : 0.0f);
        dz += (dz >= hcz) ? -cz : ((dz < -hcz) ? cz : 0.0f);

        const float dsq = dx * dx + dy * dy + dz * dz;
        if (dsq < cut2 && dsq != 0.0f) {
            const float tu = sqrtf(dsq) * invw;    // dist in bin units
            if (tu >= TLOW) {
                // ONE native u32 LDS atomic/pair; lanes scatter over 1744
                atomicAdd(&myfine[(int)(tu * (float)S_FINE)], 1u);
            } else {
                // exact f32 path for low bins (~250 pairs device-wide)
                int khi = (int)tu + 4; if (khi > NDIR - 1) khi = NDIR - 1;
                for (int k = 0; k <= khi; ++k) {
                    const float e = tu - (float)k;
                    atomicAdd(&cd[k], __expf(-0.5f * e * e));
                }
            }
        }
    }

    __syncthreads();

    // merge the 4 copies into copy 0 (stride-1, conflict-free, int adds)
    for (int a = tid; a < FBINS; a += NTHREADS)
        fine[0][a] += fine[1][a] + fine[2][a] + fine[3][a];
    __syncthreads();

    // coarse[k] = sum_d wtab[d+51] * fine[17k+d]; stride-17 reads are
    // bank-conflict free (gcd(17,32)=1)
    if (tid < 400) {
        const int k = tid >> 2;
        const int c = tid & 3;
        const int m0 = c * 26;
        const int mcnt = (c == 3) ? 25 : 26;
        float s = 0.0f;
        for (int mm = 0; mm < mcnt; ++mm) {
            const int m = m0 + mm;
            const int f = S_FINE * k + m - 51;     // max 17*99+51 = 1734
            if (f >= 0) s += wtab[m] * (float)fine[0][f];  // exact: < 2^24
        }
        conv[k][c] = s;
    }
    __syncthreads();

    // ---- publish: RETURNING atomicExch into per-block-unique slots.
    // Returning (sc0) form completes vmcnt only when the old value comes
    // back from the IF -> after the barrier all swaps are PERFORMED there.
    if (tid < NBINS) {
        float raw = conv[tid][0] + conv[tid][1] + conv[tid][2] + conv[tid][3];
        if (tid < NDIR) raw += cd[tid];
        float old = atomicExch(&partials[bid * PADB + tid], raw);
        asm volatile("" :: "v"(old));   // keep return value live (sc0 form)
    }

    __syncthreads();
    if (tid == 0) {
        const unsigned so = __hip_atomic_fetch_add(
            ticket, 1u, __ATOMIC_RELAXED, __HIP_MEMORY_SCOPE_AGENT);
        unsigned last = (so == NBLOCKS - 1) ? 1u : 0u;  // TRUE last arriver
        if (last) {
            // belt-and-braces single acquire (cache invalidate)
            __hip_atomic_fetch_add(ticket, 0u,
                                   __ATOMIC_ACQUIRE, __HIP_MEMORY_SCOPE_AGENT);
        }
        stick = last;
    }
    __syncthreads();
    if (!stick) return;

    // ---- winner (provably last): SYSTEM-scope relaxed readback at the
    // IF. thread t: bin b=t&127, chunk c=t>>7; 32 blocks each, fixed order.
    {
        const int b = tid & 127;
        const int c = tid >> 7;
        if (b < NBINS) {
            float s = 0.0f;
            #pragma unroll 8
            for (int q = 0; q < NBLOCKS / 8; ++q) {
                const int blk = c * (NBLOCKS / 8) + q;
                s += __hip_atomic_load(&partials[blk * PADB + b],
                                       __ATOMIC_RELAXED,
                                       __HIP_MEMORY_SCOPE_SYSTEM);
            }
            conv[b][c] = s;
        }
    }
    __syncthreads();

    float raw = 0.0f;
    if (tid < NBINS) {
        #pragma unroll
        for (int c = 0; c < 8; ++c) raw += conv[tid][c];
    }
    if (tid < 128) {
        float v = raw;
        #pragma unroll
        for (int o = 32; o > 0; o >>= 1) v += __shfl_down(v, o);
        if ((tid & 63) == 0) ssum[tid >> 6] = v;
    }
    __syncthreads();
    const float S = ssum[0] + ssum[1];

    if (tid < NBINS) {
        const float cnt = raw / S;
        out[tid] = cnt;                                // count
        const float b0 = bins[tid], b1 = bins[tid + 1];
        const float R  = bins[NBINS];                  // R_END = 7.5
        // rdf = cnt / (vol_bin / V) = cnt * R^3 / (b1^3 - b0^3)  (4pi/3 cancels)
        out[201 + tid] = cnt * (R * R * R) / (b1 * b1 * b1 - b0 * b0 * b0);
    }
    if (tid < NBINS + 1) {
        out[100 + tid] = bins[tid];                    // bins passthrough
    }
}

extern "C" void kernel_launch(void* const* d_in, const int* in_sizes, int n_in,
                              void* d_out, int out_size, void* d_ws, size_t ws_size,
                              hipStream_t stream) {
    const float* xyz     = (const float*)d_in[0];
    const float* cell    = (const float*)d_in[1];
    const float* bins    = (const float*)d_in[2];
    const float* offsets = (const float*)d_in[3];
    float* out = (float*)d_out;

    float*    partials = (float*)d_ws;   // NBLOCKS*PADB floats, exch-overwritten
    unsigned* ticket   = (unsigned*)((char*)d_ws +
                                     (size_t)NBLOCKS * PADB * sizeof(float));

    // single graph node: ticket reset happens INSIDE the kernel (block 0)
    rdf_fused<<<NBLOCKS, NTHREADS, 0, stream>>>(xyz, cell, offsets, bins, out,
                                                partials, ticket);
}